// Round 8
// baseline (188.298 us; speedup 1.0000x reference)
//
#include <hip/hip_runtime.h>
#include <stdint.h>

typedef unsigned short u16;
typedef __attribute__((ext_vector_type(8))) short bf16x8;
typedef __attribute__((ext_vector_type(4))) float f32x4;

__device__ __forceinline__ u16 f2bf(float f) {
    union { float f; uint32_t u; } v; v.f = f;
    uint32_t u = v.u + 0x7fffu + ((v.u >> 16) & 1u);
    return (u16)(u >> 16);
}

// packed f32x2 -> bf16x2 (hardware round)
__device__ __forceinline__ uint32_t cvtpk(float a, float b) {
    uint32_t d;
    asm("v_cvt_pk_bf16_f32 %0, %1, %2" : "=v"(d) : "v"(a), "v"(b));
    return d;
}

__device__ __forceinline__ void gld16(const void* g, void* l) {
    __builtin_amdgcn_global_load_lds((const __attribute__((address_space(1))) void*)g,
                                     (__attribute__((address_space(3))) void*)l,
                                     16, 0, 0);
}

// in-place cross-lane swap: a.row1<->b.row0, a.row3<->b.row2 (rows = 16-lane groups)
__device__ __forceinline__ void plswap16(uint32_t& a, uint32_t& b) {
    asm volatile("v_permlane16_swap_b32 %0, %1" : "+v"(a), "+v"(b));
}

// ---------------- pack kernels ----------------

__global__ void cvt_bf16_kernel(const float* __restrict__ s, u16* __restrict__ d, int n4) {
    int i = blockIdx.x * blockDim.x + threadIdx.x;
    const int stride = gridDim.x * blockDim.x;
    for (; i < n4; i += stride) {
        float4 v = ((const float4*)s)[i];
        ushort4 o;
        o.x = f2bf(v.x); o.y = f2bf(v.y); o.z = f2bf(v.z); o.w = f2bf(v.w);
        ((ushort4*)d)[i] = o;
    }
}

// dst[d][k] = src[k][d]; z selects which of the 4 weight matrices
__global__ void transpose4_bf16_kernel(const float* __restrict__ Wq, const float* __restrict__ Wk,
                                       const float* __restrict__ Wv, const float* __restrict__ Wo,
                                       u16* __restrict__ dqkv, u16* __restrict__ dо) {
    __shared__ float tile[32][33];
    const int z = blockIdx.z;
    const float* src = (z == 0) ? Wq : (z == 1) ? Wk : (z == 2) ? Wv : Wo;
    u16* dst = (z < 3) ? (dqkv + (size_t)z * 1024 * 1024) : dо;
    const int tx = threadIdx.x, ty = threadIdx.y;
    const int bx = blockIdx.x * 32, by = blockIdx.y * 32;
#pragma unroll
    for (int i = ty; i < 32; i += 8)
        tile[i][tx] = src[(size_t)(by + i) * 1024 + bx + tx];
    __syncthreads();
#pragma unroll
    for (int i = ty; i < 32; i += 8)
        dst[(size_t)(bx + i) * 1024 + by + tx] = f2bf(tile[tx][i]);
}

// ---------------- GEMM (128x128 tile, BK=32, 4 waves) ----------------

template <int EPI>
__global__ __launch_bounds__(256) void gemm128(
    const u16* __restrict__ A, const u16* __restrict__ Bt,
    const float* __restrict__ bias0, const float* __restrict__ bias1,
    const float* __restrict__ bias2,
    u16* __restrict__ o_q, u16* __restrict__ o_k, u16* __restrict__ o_vt,
    float* __restrict__ o_f)
{
    constexpr int K = 1024;
    __shared__ u16 As[128 * 32];
    __shared__ u16 Bs[128 * 32];
    const int t = threadIdx.x;
    const int lane = t & 63, w = t >> 6;
    const int wm = w >> 1, wn = w & 1;
    const int g = lane >> 4, r = lane & 15;
    const int mbase = blockIdx.y * 128, nbase = blockIdx.x * 128;

    const f32x4 zero4 = {0.f, 0.f, 0.f, 0.f};
    f32x4 acc[4][4];
#pragma unroll
    for (int m = 0; m < 4; ++m)
#pragma unroll
        for (int n = 0; n < 4; ++n) acc[m][n] = zero4;

    for (int k0 = 0; k0 < K; k0 += 32) {
#pragma unroll
        for (int i = 0; i < 2; ++i) {
            const int base = i * 256 + (w << 6);
            const int idx = base + lane;
            const int row = idx >> 2, cc = (idx & 3) << 3;
            gld16(A + (size_t)(mbase + row) * K + k0 + cc, (char*)As + base * 16);
            gld16(Bt + (size_t)(nbase + row) * K + k0 + cc, (char*)Bs + base * 16);
        }
        __syncthreads();

        bf16x8 af[4], bfr[4];
#pragma unroll
        for (int m = 0; m < 4; ++m)
            af[m] = *(const bf16x8*)&As[(wm * 64 + m * 16 + r) * 32 + g * 8];
#pragma unroll
        for (int n = 0; n < 4; ++n)
            bfr[n] = *(const bf16x8*)&Bs[(wn * 64 + n * 16 + r) * 32 + g * 8];
        __builtin_amdgcn_s_setprio(1);
#pragma unroll
        for (int m = 0; m < 4; ++m)
#pragma unroll
            for (int n = 0; n < 4; ++n)
                acc[m][n] = __builtin_amdgcn_mfma_f32_16x16x32_bf16(af[m], bfr[n], acc[m][n], 0, 0, 0);
        __builtin_amdgcn_s_setprio(0);
        __syncthreads();
    }

#pragma unroll
    for (int m = 0; m < 4; ++m) {
#pragma unroll
        for (int n = 0; n < 4; ++n) {
            const int c = nbase + wn * 64 + n * 16 + r;
#pragma unroll
            for (int j = 0; j < 4; ++j) {
                const int rr = mbase + wm * 64 + m * 16 + g * 4 + j;
                const float y = acc[m][n][j];
                if (EPI == 0) {
                    const int which = c >> 10, d = c & 1023;
                    const int b = rr >> 11, l = rr & 2047;
                    const int h = d >> 6, dd = d & 63;
                    const size_t bh = (size_t)(b * 16 + h);
                    if (which == 0) {
                        o_q[(bh * 2048 + l) * 64 + dd] = f2bf((y + bias0[d]) * 0.125f);
                    } else if (which == 1) {
                        o_k[(bh * 2048 + l) * 64 + dd] = f2bf(y + bias1[d]);
                    } else {
                        o_vt[(bh * 64 + dd) * 2048 + l] = f2bf(y + bias2[d]);
                    }
                } else {
                    o_f[(size_t)rr * 1024 + c] = y + bias0[c];
                }
            }
        }
    }
}

// ---------------- flash attention v7: 32-key tiles, 16 q-rows/wave, 8 blocks/CU ----------------
// grid: 2048 flat (64 q-tiles x 32 bh, XCD-swizzled). block: 128 (2 waves x 16 q-rows).
// LDS 16 KB/block -> 8 blocks/CU = 4 independent waves/SIMD (stall interleave).

#define ATTN_STEP(CUR, BD, BDN, PREF)                                                        \
    {                                                                                        \
        if (PREF) {                                                                          \
            const int ktn = kt + 32;                                                         \
            _Pragma("unroll")                                                                \
            for (int i = 0; i < 2; ++i) {                                                    \
                const int idx = i * 128 + t;                                                 \
                const int row = idx >> 3, ch = idx & 7;                                      \
                gld16(kb + kvBase + (size_t)(ktn + row) * 64 + ((ch ^ (row & 7)) << 3),      \
                      (char*)&Ks[CUR ^ 1][0] + idx * 16);                                    \
            }                                                                                \
            _Pragma("unroll")                                                                \
            for (int i = 0; i < 2; ++i) {                                                    \
                const int idx = i * 128 + t;                                                 \
                const int row = idx >> 2, ch = idx & 3;                                      \
                const int chs = ch ^ ((row & 3) ^ ((row >> 2) & 3));                         \
                gld16(vtb + vtBase + (size_t)row * 2048 + ktn + (chs << 3),                  \
                      (char*)&Vs[CUR ^ 1][0] + idx * 16);                                    \
            }                                                                                \
            BDN[0] = *(const float4*)&bondf[bondRowG + ktn];                                 \
            BDN[1] = *(const float4*)&bondf[bondRowG + ktn + 16];                            \
        }                                                                                    \
        bf16x8 k00, k01, k10, k11;                                                           \
        k00 = *(const bf16x8*)((const char*)&Ks[CUR][0] + (r) * 128 + ((g ^ sw) * 16));      \
        k01 = *(const bf16x8*)((const char*)&Ks[CUR][0] + (16 + r) * 128 + ((g ^ sw) * 16)); \
        k10 = *(const bf16x8*)((const char*)&Ks[CUR][0] + (r) * 128 + (((4 + g) ^ sw) * 16)); \
        k11 = *(const bf16x8*)((const char*)&Ks[CUR][0] + (16 + r) * 128 + (((4 + g) ^ sw) * 16)); \
        f32x4 st0, st1;                                                                      \
        __builtin_amdgcn_s_setprio(1);                                                       \
        st0 = __builtin_amdgcn_mfma_f32_16x16x32_bf16(k00, aq0, zero4, 0, 0, 0);             \
        st1 = __builtin_amdgcn_mfma_f32_16x16x32_bf16(k01, aq0, zero4, 0, 0, 0);             \
        st0 = __builtin_amdgcn_mfma_f32_16x16x32_bf16(k10, aq1, st0, 0, 0, 0);               \
        st1 = __builtin_amdgcn_mfma_f32_16x16x32_bf16(k11, aq1, st1, 0, 0, 0);               \
        __builtin_amdgcn_s_setprio(0);                                                       \
        const float p0 = __expf(st0[0] * BD[0].x);                                           \
        const float p1 = __expf(st0[1] * BD[0].y);                                           \
        const float p2 = __expf(st0[2] * BD[0].z);                                           \
        const float p3 = __expf(st0[3] * BD[0].w);                                           \
        const float p4 = __expf(st1[0] * BD[1].x);                                           \
        const float p5 = __expf(st1[1] * BD[1].y);                                           \
        const float p6 = __expf(st1[2] * BD[1].z);                                           \
        const float p7 = __expf(st1[3] * BD[1].w);                                           \
        sm += ((p0 + p1) + (p2 + p3)) + ((p4 + p5) + (p6 + p7));                             \
        uint32_t l0 = cvtpk(p0, p1), h0 = cvtpk(p2, p3);                                     \
        uint32_t l1 = cvtpk(p4, p5), h1 = cvtpk(p6, p7);                                     \
        plswap16(l0, l1);                                                                    \
        plswap16(h0, h1);                                                                    \
        union { uint32_t u[4]; bf16x8 v; } ap_;                                              \
        ap_.u[0] = l0; ap_.u[1] = h0; ap_.u[2] = l1; ap_.u[3] = h1;                          \
        bf16x8 bv0, bv1, bv2, bv3;                                                           \
        bv0 = *(const bf16x8*)((const char*)&Vs[CUR][0] + (r) * 64 + ((pg ^ sv) * 16));      \
        bv1 = *(const bf16x8*)((const char*)&Vs[CUR][0] + (16 + r) * 64 + ((pg ^ sv) * 16)); \
        bv2 = *(const bf16x8*)((const char*)&Vs[CUR][0] + (32 + r) * 64 + ((pg ^ sv) * 16)); \
        bv3 = *(const bf16x8*)((const char*)&Vs[CUR][0] + (48 + r) * 64 + ((pg ^ sv) * 16)); \
        __builtin_amdgcn_s_setprio(1);                                                       \
        o0 = __builtin_amdgcn_mfma_f32_16x16x32_bf16(ap_.v, bv0, o0, 0, 0, 0);               \
        o1 = __builtin_amdgcn_mfma_f32_16x16x32_bf16(ap_.v, bv1, o1, 0, 0, 0);               \
        o2 = __builtin_amdgcn_mfma_f32_16x16x32_bf16(ap_.v, bv2, o2, 0, 0, 0);               \
        o3 = __builtin_amdgcn_mfma_f32_16x16x32_bf16(ap_.v, bv3, o3, 0, 0, 0);               \
        __builtin_amdgcn_s_setprio(0);                                                       \
        __syncthreads();                                                                     \
        kt += 32;                                                                            \
    }

__global__ __launch_bounds__(128, 4) void attn_kernel(
    const u16* __restrict__ qb, const u16* __restrict__ kb,
    const u16* __restrict__ vtb, const float* __restrict__ bondf,
    u16* __restrict__ attnout)
{
    __shared__ u16 Ks[2][32 * 64];   // [buf][key][dk]    swizzle: ch ^ (row&7)
    __shared__ u16 Vs[2][64 * 32];   // [buf][dk][key]    swizzle: ch ^ ((row&3)^((row>>2)&3))
    const int t = threadIdx.x;
    const int lane = t & 63, w = t >> 6;
    const int g = lane >> 4, r = lane & 15;
    const int sw = r & 7;
    const int sv = (r & 3) ^ ((r >> 2) & 3);
    const int pg = ((g & 1) << 1) | (g >> 1);   // key-chunk perm from permlane16_swap
    const int flat = blockIdx.x;
    const int wg = (flat & 7) * 256 + (flat >> 3);
    const int bh = wg >> 6, qt = wg & 63;
    const int b = bh >> 4, h = bh & 15;
    const int q0 = qt * 32 + w * 16;
    const size_t kvBase = (size_t)bh * 2048 * 64;
    const size_t vtBase = (size_t)bh * 64 * 2048;
    const size_t bondRowG = ((size_t)b * 2048 + q0 + r) * 2048 + g * 4;

    // Q as B-operand fragments: lane gives Q[q0+r][kz*32+g*8+jj]
    const bf16x8 aq0 = *(const bf16x8*)&qb[kvBase + (size_t)(q0 + r) * 64 + g * 8];
    const bf16x8 aq1 = *(const bf16x8*)&qb[kvBase + (size_t)(q0 + r) * 64 + 32 + g * 8];

    const f32x4 zero4 = {0.f, 0.f, 0.f, 0.f};
    f32x4 o0 = zero4, o1 = zero4, o2 = zero4, o3 = zero4;
    float sm = 0.f;

    // prologue: stage tile 0 into buf0; bond tile 0 into A regs
#pragma unroll
    for (int i = 0; i < 2; ++i) {
        const int idx = i * 128 + t;
        const int row = idx >> 3, ch = idx & 7;
        gld16(kb + kvBase + (size_t)row * 64 + ((ch ^ (row & 7)) << 3),
              (char*)&Ks[0][0] + idx * 16);
    }
#pragma unroll
    for (int i = 0; i < 2; ++i) {
        const int idx = i * 128 + t;
        const int row = idx >> 2, ch = idx & 3;
        const int chs = ch ^ ((row & 3) ^ ((row >> 2) & 3));
        gld16(vtb + vtBase + (size_t)row * 2048 + (chs << 3),
              (char*)&Vs[0][0] + idx * 16);
    }
    float4 bdA[2], bdB[2];
    bdA[0] = *(const float4*)&bondf[bondRowG];
    bdA[1] = *(const float4*)&bondf[bondRowG + 16];
    __syncthreads();

    int kt = 0;
    for (int s = 0; s < 32; ++s) {
        ATTN_STEP(0, bdA, bdB, true)
        ATTN_STEP(1, bdB, bdA, (s < 31))
    }

    // row sums: reduce across the 4 g-groups, redistribute via width-16 shuffle
    sm += __shfl_xor(sm, 16, 64);
    sm += __shfl_xor(sm, 32, 64);
#pragma unroll
    for (int j = 0; j < 4; ++j) {
        const float inv = 1.f / __shfl(sm, g * 4 + j, 16);
        const size_t orow = ((size_t)b * 2048 + q0 + g * 4 + j) * 1024 + h * 64;
        attnout[orow + r]      = f2bf(o0[j] * inv);
        attnout[orow + 16 + r] = f2bf(o1[j] * inv);
        attnout[orow + 32 + r] = f2bf(o2[j] * inv);
        attnout[orow + 48 + r] = f2bf(o3[j] * inv);
    }
}

// ---------------- launch ----------------

extern "C" void kernel_launch(void* const* d_in, const int* in_sizes, int n_in,
                              void* d_out, int out_size, void* d_ws, size_t ws_size,
                              hipStream_t stream) {
    (void)in_sizes; (void)n_in; (void)out_size; (void)ws_size;
    const float* x    = (const float*)d_in[0];
    const float* bond = (const float*)d_in[1];
    const float* Wq   = (const float*)d_in[2];
    const float* bq   = (const float*)d_in[3];
    const float* Wk   = (const float*)d_in[4];
    const float* bk   = (const float*)d_in[5];
    const float* Wv   = (const float*)d_in[6];
    const float* bv   = (const float*)d_in[7];
    const float* Wo   = (const float*)d_in[8];
    const float* bo   = (const float*)d_in[9];
    float* out = (float*)d_out;

    char* ws = (char*)d_ws;
    u16* xb      = (u16*)(ws);
    u16* wqkvt   = (u16*)(ws + 8388608);
    u16* wot     = (u16*)(ws + 14680064);
    u16* qb      = (u16*)(ws + 16777216);
    u16* kb_     = (u16*)(ws + 25165824);
    u16* vtb     = (u16*)(ws + 33554432);
    u16* attnout = (u16*)(ws + 58720256);

    dim3 tb(32, 8);
    transpose4_bf16_kernel<<<dim3(32, 32, 4), tb, 0, stream>>>(Wq, Wk, Wv, Wo, wqkvt, wot);
    cvt_bf16_kernel<<<1024, 256, 0, stream>>>(x, xb, 4194304 / 4);

    gemm128<0><<<dim3(24, 32), 256, 0, stream>>>(xb, wqkvt, bq, bk, bv, qb, kb_, vtb, nullptr);
    attn_kernel<<<dim3(2048), 128, 0, stream>>>(qb, kb_, vtb, bond, attnout);
    gemm128<1><<<dim3(8, 32), 256, 0, stream>>>(attnout, wot, bo, nullptr, nullptr,
                                                nullptr, nullptr, nullptr, out);
}

// Round 9
// 184.412 us; speedup vs baseline: 1.0211x; 1.0211x over previous
//
#include <hip/hip_runtime.h>
#include <stdint.h>

typedef unsigned short u16;
typedef __attribute__((ext_vector_type(8))) short bf16x8;
typedef __attribute__((ext_vector_type(4))) float f32x4;

__device__ __forceinline__ u16 f2bf(float f) {
    union { float f; uint32_t u; } v; v.f = f;
    uint32_t u = v.u + 0x7fffu + ((v.u >> 16) & 1u);
    return (u16)(u >> 16);
}
__device__ __forceinline__ float bf2f(u16 s) {
    union { uint32_t u; float f; } v; v.u = ((uint32_t)s) << 16;
    return v.f;
}
// hardware 2^x (VALU transcendental, hw-interlocked)
__device__ __forceinline__ float vexp2(float x) {
    float d;
    asm("v_exp_f32 %0, %1" : "=v"(d) : "v"(x));
    return d;
}

__device__ __forceinline__ void gld16(const void* g, void* l) {
    __builtin_amdgcn_global_load_lds((const __attribute__((address_space(1))) void*)g,
                                     (__attribute__((address_space(3))) void*)l,
                                     16, 0, 0);
}

// in-place cross-lane swap: a.row1<->b.row0, a.row3<->b.row2 (rows = 16-lane groups)
__device__ __forceinline__ void plswap16(uint32_t& a, uint32_t& b) {
    asm volatile("v_permlane16_swap_b32 %0, %1" : "+v"(a), "+v"(b));
}
// fast positive-value pack: round-half-up (bias only on exact ties)
__device__ __forceinline__ uint32_t packbf(float a, float b) {
    union { float f; uint32_t u; } ua, ub; ua.f = a; ub.f = b;
    return ((ua.u + 0x8000u) >> 16) | ((ub.u + 0x8000u) & 0xffff0000u);
}

// ---------------- pack kernels ----------------

__global__ void cvt_bf16_kernel(const float* __restrict__ s, u16* __restrict__ d, int n4,
                                float scale) {
    int i = blockIdx.x * blockDim.x + threadIdx.x;
    const int stride = gridDim.x * blockDim.x;
    for (; i < n4; i += stride) {
        float4 v = ((const float4*)s)[i];
        ushort4 o;
        o.x = f2bf(v.x * scale); o.y = f2bf(v.y * scale);
        o.z = f2bf(v.z * scale); o.w = f2bf(v.w * scale);
        ((ushort4*)d)[i] = o;
    }
}

// dst[d][k] = src[k][d]; z selects which of the 4 weight matrices
__global__ void transpose4_bf16_kernel(const float* __restrict__ Wq, const float* __restrict__ Wk,
                                       const float* __restrict__ Wv, const float* __restrict__ Wo,
                                       u16* __restrict__ dqkv, u16* __restrict__ dо) {
    __shared__ float tile[32][33];
    const int z = blockIdx.z;
    const float* src = (z == 0) ? Wq : (z == 1) ? Wk : (z == 2) ? Wv : Wo;
    u16* dst = (z < 3) ? (dqkv + (size_t)z * 1024 * 1024) : dо;
    const int tx = threadIdx.x, ty = threadIdx.y;
    const int bx = blockIdx.x * 32, by = blockIdx.y * 32;
#pragma unroll
    for (int i = ty; i < 32; i += 8)
        tile[i][tx] = src[(size_t)(by + i) * 1024 + bx + tx];
    __syncthreads();
#pragma unroll
    for (int i = ty; i < 32; i += 8)
        dst[(size_t)(bx + i) * 1024 + by + tx] = f2bf(tile[tx][i]);
}

// ---------------- GEMM (128x128 tile, BK=32, 4 waves) ----------------

template <int EPI>
__global__ __launch_bounds__(256) void gemm128(
    const u16* __restrict__ A, const u16* __restrict__ Bt,
    const float* __restrict__ bias0, const float* __restrict__ bias1,
    const float* __restrict__ bias2,
    u16* __restrict__ o_q, u16* __restrict__ o_k, u16* __restrict__ o_vt,
    float* __restrict__ o_f)
{
    constexpr int K = 1024;
    __shared__ u16 As[128 * 32];
    __shared__ u16 Bs[128 * 32];
    const int t = threadIdx.x;
    const int lane = t & 63, w = t >> 6;
    const int wm = w >> 1, wn = w & 1;
    const int g = lane >> 4, r = lane & 15;
    const int mbase = blockIdx.y * 128, nbase = blockIdx.x * 128;

    const f32x4 zero4 = {0.f, 0.f, 0.f, 0.f};
    f32x4 acc[4][4];
#pragma unroll
    for (int m = 0; m < 4; ++m)
#pragma unroll
        for (int n = 0; n < 4; ++n) acc[m][n] = zero4;

    for (int k0 = 0; k0 < K; k0 += 32) {
#pragma unroll
        for (int i = 0; i < 2; ++i) {
            const int base = i * 256 + (w << 6);
            const int idx = base + lane;
            const int row = idx >> 2, cc = (idx & 3) << 3;
            gld16(A + (size_t)(mbase + row) * K + k0 + cc, (char*)As + base * 16);
            gld16(Bt + (size_t)(nbase + row) * K + k0 + cc, (char*)Bs + base * 16);
        }
        __syncthreads();

        bf16x8 af[4], bfr[4];
#pragma unroll
        for (int m = 0; m < 4; ++m)
            af[m] = *(const bf16x8*)&As[(wm * 64 + m * 16 + r) * 32 + g * 8];
#pragma unroll
        for (int n = 0; n < 4; ++n)
            bfr[n] = *(const bf16x8*)&Bs[(wn * 64 + n * 16 + r) * 32 + g * 8];
        __builtin_amdgcn_s_setprio(1);
#pragma unroll
        for (int m = 0; m < 4; ++m)
#pragma unroll
            for (int n = 0; n < 4; ++n)
                acc[m][n] = __builtin_amdgcn_mfma_f32_16x16x32_bf16(af[m], bfr[n], acc[m][n], 0, 0, 0);
        __builtin_amdgcn_s_setprio(0);
        __syncthreads();
    }

#pragma unroll
    for (int m = 0; m < 4; ++m) {
#pragma unroll
        for (int n = 0; n < 4; ++n) {
            const int c = nbase + wn * 64 + n * 16 + r;
#pragma unroll
            for (int j = 0; j < 4; ++j) {
                const int rr = mbase + wm * 64 + m * 16 + g * 4 + j;
                const float y = acc[m][n][j];
                if (EPI == 0) {
                    const int which = c >> 10, d = c & 1023;
                    const int b = rr >> 11, l = rr & 2047;
                    const int h = d >> 6, dd = d & 63;
                    const size_t bh = (size_t)(b * 16 + h);
                    if (which == 0) {
                        o_q[(bh * 2048 + l) * 64 + dd] = f2bf((y + bias0[d]) * 0.125f);
                    } else if (which == 1) {
                        o_k[(bh * 2048 + l) * 64 + dd] = f2bf(y + bias1[d]);
                    } else {
                        o_vt[(bh * 64 + dd) * 2048 + l] = f2bf(y + bias2[d]);
                    }
                } else {
                    o_f[(size_t)rr * 1024 + c] = y + bias0[c];
                }
            }
        }
    }
}

// ---------------- flash attention v8: R6 structure, bf16 bond (log2e-folded) ----------------
// grid: 1024 flat (32 q-tiles x 32 bh, XCD-swizzled). block: 128 (2 waves x 32 q-rows).

__global__ __launch_bounds__(128, 2) void attn_kernel(
    const u16* __restrict__ qb, const u16* __restrict__ kb,
    const u16* __restrict__ vtb, const u16* __restrict__ bondb,
    u16* __restrict__ attnout)
{
    __shared__ u16 Ks[2][64 * 64];   // [buf][key][dk]   swizzled chunks
    __shared__ u16 Vs[2][64 * 64];   // [buf][dk][key]   swizzled chunks
    const int t = threadIdx.x;
    const int lane = t & 63, w = t >> 6;
    const int g = lane >> 4, r = lane & 15;
    const int sw = r & 7;
    const int pg = ((g & 1) << 1) | (g >> 1);   // key-chunk permutation from permlane16_swap
    const int flat = blockIdx.x;
    const int wg = (flat & 7) * 128 + (flat >> 3);
    const int bh = wg >> 5, qt = wg & 31;
    const int b = bh >> 4, h = bh & 15;
    const int q0 = qt * 64 + w * 32;
    const size_t kvBase = (size_t)bh * 2048 * 64;
    const size_t bondRow0 = ((size_t)b * 2048 + q0 + r) * 2048;   // qf adds 16*2048

    // Q as B-operand fragments: lane gives Q[q0+qf*16+r][kz*32+g*8+jj]
    bf16x8 aq[2][2];
#pragma unroll
    for (int qf = 0; qf < 2; ++qf)
#pragma unroll
        for (int kz = 0; kz < 2; ++kz)
            aq[qf][kz] = *(const bf16x8*)&qb[kvBase + (size_t)(q0 + qf * 16 + r) * 64 + kz * 32 + g * 8];

    const f32x4 zero4 = {0.f, 0.f, 0.f, 0.f};
    f32x4 o[2][4];
#pragma unroll
    for (int qf = 0; qf < 2; ++qf)
#pragma unroll
        for (int nf = 0; nf < 4; ++nf) o[qf][nf] = zero4;
    float sm[2] = {0.f, 0.f};

    // prologue: stage K/V tile 0; bond tile 0 into registers
#pragma unroll
    for (int i = 0; i < 4; ++i) {
        const int idx = i * 128 + t;
        const int row = idx >> 3, ch = idx & 7;
        const int chg = ch ^ (row & 7);
        gld16(kb + kvBase + (size_t)row * 64 + chg * 8, (char*)&Ks[0][0] + idx * 16);
        gld16(vtb + ((size_t)bh * 64 + row) * 2048 + chg * 8, (char*)&Vs[0][0] + idx * 16);
    }
    ushort4 bd[2][4], bdn[2][4];
#pragma unroll
    for (int qf = 0; qf < 2; ++qf)
#pragma unroll
        for (int kf = 0; kf < 4; ++kf)
            bd[qf][kf] = *(const ushort4*)&bondb[bondRow0 + (size_t)qf * 16 * 2048 + kf * 16 + g * 4];
    __syncthreads();

    for (int it = 0; it < 32; ++it) {
        const int cur = it & 1;
        const int kt = it * 64;
        // phase 1: issue K/V prefetch for t+1 (stays in flight through compute)
        if (it < 31) {
            const int kt2 = kt + 64;
#pragma unroll
            for (int i = 0; i < 4; ++i) {
                const int idx = i * 128 + t;
                const int row = idx >> 3, ch = idx & 7;
                const int chg = ch ^ (row & 7);
                gld16(kb + kvBase + (size_t)(kt2 + row) * 64 + chg * 8, (char*)&Ks[cur ^ 1][0] + idx * 16);
                gld16(vtb + ((size_t)bh * 64 + row) * 2048 + kt2 + chg * 8, (char*)&Vs[cur ^ 1][0] + idx * 16);
            }
            // phase 2: issue bond loads for t+1 into regs (wait lands after compute)
#pragma unroll
            for (int qf = 0; qf < 2; ++qf)
#pragma unroll
                for (int kf = 0; kf < 4; ++kf)
                    bdn[qf][kf] = *(const ushort4*)&bondb[bondRow0 + (size_t)qf * 16 * 2048 + kt2 + kf * 16 + g * 4];
        }

        // phase 3: QK^T for kf=0,1 (keys 0..31)
        f32x4 st[2][4];
        {
            bf16x8 kfr[2][2];
#pragma unroll
            for (int kz = 0; kz < 2; ++kz)
#pragma unroll
                for (int kf = 0; kf < 2; ++kf)
                    kfr[kz][kf] = *(const bf16x8*)((const char*)&Ks[cur][0] +
                                    (kf * 16 + r) * 128 + (((kz * 4 + g) ^ sw) * 16));
#pragma unroll
            for (int qf = 0; qf < 2; ++qf)
#pragma unroll
                for (int kf = 0; kf < 2; ++kf) st[qf][kf] = zero4;
            __builtin_amdgcn_s_setprio(1);
#pragma unroll
            for (int kz = 0; kz < 2; ++kz)
#pragma unroll
                for (int qf = 0; qf < 2; ++qf)
#pragma unroll
                    for (int kf = 0; kf < 2; ++kf)
                        st[qf][kf] = __builtin_amdgcn_mfma_f32_16x16x32_bf16(kfr[kz][kf], aq[qf][kz], st[qf][kf], 0, 0, 0);
            __builtin_amdgcn_s_setprio(0);
        }

        // phase 4: p = exp2(s * bond_l2e) kf=0,1; permlane into PV A-frag ap0
        bf16x8 ap0[2], ap1[2];
#pragma unroll
        for (int qf = 0; qf < 2; ++qf) {
            uint32_t pkl[2], pkh[2];
#pragma unroll
            for (int kf = 0; kf < 2; ++kf) {
                const float p0 = vexp2(st[qf][kf][0] * bf2f(bd[qf][kf].x));
                const float p1 = vexp2(st[qf][kf][1] * bf2f(bd[qf][kf].y));
                const float p2 = vexp2(st[qf][kf][2] * bf2f(bd[qf][kf].z));
                const float p3 = vexp2(st[qf][kf][3] * bf2f(bd[qf][kf].w));
                sm[qf] += (p0 + p1) + (p2 + p3);
                pkl[kf] = packbf(p0, p1);
                pkh[kf] = packbf(p2, p3);
            }
            plswap16(pkl[0], pkl[1]);
            plswap16(pkh[0], pkh[1]);
            union { uint32_t u[4]; bf16x8 v; } a;
            a.u[0] = pkl[0]; a.u[1] = pkh[0]; a.u[2] = pkl[1]; a.u[3] = pkh[1];
            ap0[qf] = a.v;
        }

        // phase 5: QK^T for kf=2,3
        {
            bf16x8 kfr[2][2];
#pragma unroll
            for (int kz = 0; kz < 2; ++kz)
#pragma unroll
                for (int kf = 0; kf < 2; ++kf)
                    kfr[kz][kf] = *(const bf16x8*)((const char*)&Ks[cur][0] +
                                    ((kf + 2) * 16 + r) * 128 + (((kz * 4 + g) ^ sw) * 16));
#pragma unroll
            for (int qf = 0; qf < 2; ++qf)
#pragma unroll
                for (int kf = 0; kf < 2; ++kf) st[qf][kf + 2] = zero4;
            __builtin_amdgcn_s_setprio(1);
#pragma unroll
            for (int kz = 0; kz < 2; ++kz)
#pragma unroll
                for (int qf = 0; qf < 2; ++qf)
#pragma unroll
                    for (int kf = 0; kf < 2; ++kf)
                        st[qf][kf + 2] = __builtin_amdgcn_mfma_f32_16x16x32_bf16(kfr[kz][kf], aq[qf][kz], st[qf][kf + 2], 0, 0, 0);
            __builtin_amdgcn_s_setprio(0);
        }

        // phase 6: PV kz=0 (keys 0..31; V chunk pg matches permuted key order)
        {
            bf16x8 bv_[4];
#pragma unroll
            for (int nf = 0; nf < 4; ++nf)
                bv_[nf] = *(const bf16x8*)((const char*)&Vs[cur][0] +
                            (nf * 16 + r) * 128 + ((pg ^ sw) * 16));
            __builtin_amdgcn_s_setprio(1);
#pragma unroll
            for (int qf = 0; qf < 2; ++qf)
#pragma unroll
                for (int nf = 0; nf < 4; ++nf)
                    o[qf][nf] = __builtin_amdgcn_mfma_f32_16x16x32_bf16(ap0[qf], bv_[nf], o[qf][nf], 0, 0, 0);
            __builtin_amdgcn_s_setprio(0);
        }

        // phase 7: exp kf=2,3 -> ap1 (keys 32..63)
#pragma unroll
        for (int qf = 0; qf < 2; ++qf) {
            uint32_t pkl[2], pkh[2];
#pragma unroll
            for (int kf = 0; kf < 2; ++kf) {
                const float p0 = vexp2(st[qf][kf + 2][0] * bf2f(bd[qf][kf + 2].x));
                const float p1 = vexp2(st[qf][kf + 2][1] * bf2f(bd[qf][kf + 2].y));
                const float p2 = vexp2(st[qf][kf + 2][2] * bf2f(bd[qf][kf + 2].z));
                const float p3 = vexp2(st[qf][kf + 2][3] * bf2f(bd[qf][kf + 2].w));
                sm[qf] += (p0 + p1) + (p2 + p3);
                pkl[kf] = packbf(p0, p1);
                pkh[kf] = packbf(p2, p3);
            }
            plswap16(pkl[0], pkl[1]);
            plswap16(pkh[0], pkh[1]);
            union { uint32_t u[4]; bf16x8 v; } a;
            a.u[0] = pkl[0]; a.u[1] = pkh[0]; a.u[2] = pkl[1]; a.u[3] = pkh[1];
            ap1[qf] = a.v;
        }

        // phase 8: PV kz=1 (keys 32..63)
        {
            bf16x8 bv_[4];
#pragma unroll
            for (int nf = 0; nf < 4; ++nf)
                bv_[nf] = *(const bf16x8*)((const char*)&Vs[cur][0] +
                            (nf * 16 + r) * 128 + (((4 + pg) ^ sw) * 16));
            __builtin_amdgcn_s_setprio(1);
#pragma unroll
            for (int qf = 0; qf < 2; ++qf)
#pragma unroll
                for (int nf = 0; nf < 4; ++nf)
                    o[qf][nf] = __builtin_amdgcn_mfma_f32_16x16x32_bf16(ap1[qf], bv_[nf], o[qf][nf], 0, 0, 0);
            __builtin_amdgcn_s_setprio(0);
        }

        // phase 9: rotate bond regs (forces the bond-load wait here, after compute)
        if (it < 31) {
#pragma unroll
            for (int qf = 0; qf < 2; ++qf)
#pragma unroll
                for (int kf = 0; kf < 4; ++kf)
                    bd[qf][kf] = bdn[qf][kf];
        }
        __syncthreads();
    }

    // row sums: reduce across the 4 g-groups, redistribute via width-16 shuffle
#pragma unroll
    for (int qf = 0; qf < 2; ++qf) {
        sm[qf] += __shfl_xor(sm[qf], 16, 64);
        sm[qf] += __shfl_xor(sm[qf], 32, 64);
    }
#pragma unroll
    for (int qf = 0; qf < 2; ++qf)
#pragma unroll
        for (int j = 0; j < 4; ++j) {
            const float inv = 1.f / __shfl(sm[qf], g * 4 + j, 16);
            const size_t orow = ((size_t)b * 2048 + q0 + qf * 16 + g * 4 + j) * 1024 + h * 64;
#pragma unroll
            for (int nf = 0; nf < 4; ++nf)
                attnout[orow + nf * 16 + r] = f2bf(o[qf][nf][j] * inv);
        }
}

// ---------------- launch ----------------

extern "C" void kernel_launch(void* const* d_in, const int* in_sizes, int n_in,
                              void* d_out, int out_size, void* d_ws, size_t ws_size,
                              hipStream_t stream) {
    (void)in_sizes; (void)n_in; (void)out_size; (void)ws_size;
    const float* x    = (const float*)d_in[0];
    const float* bond = (const float*)d_in[1];
    const float* Wq   = (const float*)d_in[2];
    const float* bq   = (const float*)d_in[3];
    const float* Wk   = (const float*)d_in[4];
    const float* bk   = (const float*)d_in[5];
    const float* Wv   = (const float*)d_in[6];
    const float* bv   = (const float*)d_in[7];
    const float* Wo   = (const float*)d_in[8];
    const float* bo   = (const float*)d_in[9];
    float* out = (float*)d_out;

    char* ws = (char*)d_ws;
    u16* xb      = (u16*)(ws);
    u16* wqkvt   = (u16*)(ws + 8388608);
    u16* wot     = (u16*)(ws + 14680064);
    u16* qb      = (u16*)(ws + 16777216);
    u16* kb_     = (u16*)(ws + 25165824);
    u16* vtb     = (u16*)(ws + 33554432);
    u16* bondb   = (u16*)(ws + 41943040);
    u16* attnout = (u16*)(ws + 58720256);

    dim3 tb(32, 8);
    transpose4_bf16_kernel<<<dim3(32, 32, 4), tb, 0, stream>>>(Wq, Wk, Wv, Wo, wqkvt, wot);
    cvt_bf16_kernel<<<1024, 256, 0, stream>>>(x, xb, 4194304 / 4, 1.0f);
    cvt_bf16_kernel<<<2048, 256, 0, stream>>>(bond, bondb, 8388608 / 4, 1.4426950408889634f);

    gemm128<0><<<dim3(24, 32), 256, 0, stream>>>(xb, wqkvt, bq, bk, bv, qb, kb_, vtb, nullptr);
    attn_kernel<<<dim3(1024), 128, 0, stream>>>(qb, kb_, vtb, bondb, attnout);
    gemm128<1><<<dim3(8, 32), 256, 0, stream>>>(attnout, wot, bo, nullptr, nullptr,
                                                nullptr, nullptr, nullptr, out);
}

// Round 10
// 163.335 us; speedup vs baseline: 1.1528x; 1.1290x over previous
//
#include <hip/hip_runtime.h>
#include <stdint.h>

typedef unsigned short u16;
typedef __attribute__((ext_vector_type(8))) short bf16x8;
typedef __attribute__((ext_vector_type(4))) float f32x4;

__device__ __forceinline__ u16 f2bf(float f) {
    union { float f; uint32_t u; } v; v.f = f;
    uint32_t u = v.u + 0x7fffu + ((v.u >> 16) & 1u);
    return (u16)(u >> 16);
}
// hardware 2^x
__device__ __forceinline__ float vexp2(float x) {
    float d;
    asm("v_exp_f32 %0, %1" : "=v"(d) : "v"(x));
    return d;
}
// packed f32x2 -> bf16x2 (hardware round)
__device__ __forceinline__ uint32_t cvtpk(float a, float b) {
    uint32_t d;
    asm("v_cvt_pk_bf16_f32 %0, %1, %2" : "=v"(d) : "v"(a), "v"(b));
    return d;
}

__device__ __forceinline__ void gld16(const void* g, void* l) {
    __builtin_amdgcn_global_load_lds((const __attribute__((address_space(1))) void*)g,
                                     (__attribute__((address_space(3))) void*)l,
                                     16, 0, 0);
}

// in-place cross-lane swap: a.row1<->b.row0, a.row3<->b.row2 (rows = 16-lane groups)
__device__ __forceinline__ void plswap16(uint32_t& a, uint32_t& b) {
    asm volatile("v_permlane16_swap_b32 %0, %1" : "+v"(a), "+v"(b));
}

// ---------------- pack kernels ----------------

__global__ void cvt_bf16_kernel(const float* __restrict__ s, u16* __restrict__ d, int n4,
                                float scale) {
    int i = blockIdx.x * blockDim.x + threadIdx.x;
    const int stride = gridDim.x * blockDim.x;
    for (; i < n4; i += stride) {
        float4 v = ((const float4*)s)[i];
        ushort4 o;
        o.x = f2bf(v.x * scale); o.y = f2bf(v.y * scale);
        o.z = f2bf(v.z * scale); o.w = f2bf(v.w * scale);
        ((ushort4*)d)[i] = o;
    }
}

// dst[d][k] = src[k][d]; z selects which of the 4 weight matrices
__global__ void transpose4_bf16_kernel(const float* __restrict__ Wq, const float* __restrict__ Wk,
                                       const float* __restrict__ Wv, const float* __restrict__ Wo,
                                       u16* __restrict__ dqkv, u16* __restrict__ dо) {
    __shared__ float tile[32][33];
    const int z = blockIdx.z;
    const float* src = (z == 0) ? Wq : (z == 1) ? Wk : (z == 2) ? Wv : Wo;
    u16* dst = (z < 3) ? (dqkv + (size_t)z * 1024 * 1024) : dо;
    const int tx = threadIdx.x, ty = threadIdx.y;
    const int bx = blockIdx.x * 32, by = blockIdx.y * 32;
#pragma unroll
    for (int i = ty; i < 32; i += 8)
        tile[i][tx] = src[(size_t)(by + i) * 1024 + bx + tx];
    __syncthreads();
#pragma unroll
    for (int i = ty; i < 32; i += 8)
        dst[(size_t)(bx + i) * 1024 + by + tx] = f2bf(tile[tx][i]);
}

// ---------------- GEMM (128x128 tile, BK=32, 4 waves) ----------------

template <int EPI>
__global__ __launch_bounds__(256) void gemm128(
    const u16* __restrict__ A, const u16* __restrict__ Bt,
    const float* __restrict__ bias0, const float* __restrict__ bias1,
    const float* __restrict__ bias2,
    u16* __restrict__ o_q, u16* __restrict__ o_k, u16* __restrict__ o_vt,
    float* __restrict__ o_f)
{
    constexpr int K = 1024;
    __shared__ u16 As[128 * 32];
    __shared__ u16 Bs[128 * 32];
    const int t = threadIdx.x;
    const int lane = t & 63, w = t >> 6;
    const int wm = w >> 1, wn = w & 1;
    const int g = lane >> 4, r = lane & 15;
    const int mbase = blockIdx.y * 128, nbase = blockIdx.x * 128;

    const f32x4 zero4 = {0.f, 0.f, 0.f, 0.f};
    f32x4 acc[4][4];
#pragma unroll
    for (int m = 0; m < 4; ++m)
#pragma unroll
        for (int n = 0; n < 4; ++n) acc[m][n] = zero4;

    for (int k0 = 0; k0 < K; k0 += 32) {
#pragma unroll
        for (int i = 0; i < 2; ++i) {
            const int base = i * 256 + (w << 6);
            const int idx = base + lane;
            const int row = idx >> 2, cc = (idx & 3) << 3;
            gld16(A + (size_t)(mbase + row) * K + k0 + cc, (char*)As + base * 16);
            gld16(Bt + (size_t)(nbase + row) * K + k0 + cc, (char*)Bs + base * 16);
        }
        __syncthreads();

        bf16x8 af[4], bfr[4];
#pragma unroll
        for (int m = 0; m < 4; ++m)
            af[m] = *(const bf16x8*)&As[(wm * 64 + m * 16 + r) * 32 + g * 8];
#pragma unroll
        for (int n = 0; n < 4; ++n)
            bfr[n] = *(const bf16x8*)&Bs[(wn * 64 + n * 16 + r) * 32 + g * 8];
        __builtin_amdgcn_s_setprio(1);
#pragma unroll
        for (int m = 0; m < 4; ++m)
#pragma unroll
            for (int n = 0; n < 4; ++n)
                acc[m][n] = __builtin_amdgcn_mfma_f32_16x16x32_bf16(af[m], bfr[n], acc[m][n], 0, 0, 0);
        __builtin_amdgcn_s_setprio(0);
        __syncthreads();
    }

#pragma unroll
    for (int m = 0; m < 4; ++m) {
#pragma unroll
        for (int n = 0; n < 4; ++n) {
            const int c = nbase + wn * 64 + n * 16 + r;
#pragma unroll
            for (int j = 0; j < 4; ++j) {
                const int rr = mbase + wm * 64 + m * 16 + g * 4 + j;
                const float y = acc[m][n][j];
                if (EPI == 0) {
                    const int which = c >> 10, d = c & 1023;
                    const int b = rr >> 11, l = rr & 2047;
                    const int h = d >> 6, dd = d & 63;
                    const size_t bh = (size_t)(b * 16 + h);
                    if (which == 0) {
                        // Q pre-scale: 1/sqrt(64) * log2(e), so attn uses exp2 directly
                        o_q[(bh * 2048 + l) * 64 + dd] = f2bf((y + bias0[d]) * 0.18033688011112042f);
                    } else if (which == 1) {
                        o_k[(bh * 2048 + l) * 64 + dd] = f2bf(y + bias1[d]);
                    } else {
                        o_vt[(bh * 64 + dd) * 2048 + l] = f2bf(y + bias2[d]);
                    }
                } else {
                    o_f[(size_t)rr * 1024 + c] = y + bias0[c];
                }
            }
        }
    }
}

// ---------------- flash attention v9: counted-vmcnt, raw barriers, no drain ----------------
// grid: 1024 flat (32 q-tiles x 32 bh, XCD-swizzled). block: 128 (2 waves x 32 q-rows).
// Per iter: 16 vmem issued (8 gld16 + 8 bond float4). Top-of-iter s_waitcnt vmcnt(16)
// waits ONLY for tile-t's loads; tile-t+1's 16 remain in flight across both barriers.

#define ATTN_STEP(CUR, BD, BDN, PREF, WAITN)                                                 \
    {                                                                                        \
        if (PREF) {                                                                          \
            const int kt2 = kt + 64;                                                         \
            _Pragma("unroll")                                                                \
            for (int i = 0; i < 4; ++i) {                                                    \
                const int idx = i * 128 + t;                                                 \
                const int row = idx >> 3, ch = idx & 7;                                      \
                const int chg = ch ^ (row & 7);                                              \
                gld16(kb + kvBase + (size_t)(kt2 + row) * 64 + chg * 8,                      \
                      (char*)&Ks[CUR ^ 1][0] + idx * 16);                                    \
                gld16(vtb + vtBase + (size_t)row * 2048 + kt2 + chg * 8,                     \
                      (char*)&Vs[CUR ^ 1][0] + idx * 16);                                    \
            }                                                                                \
            _Pragma("unroll")                                                                \
            for (int qf = 0; qf < 2; ++qf)                                                   \
                _Pragma("unroll")                                                            \
                for (int kf = 0; kf < 4; ++kf)                                               \
                    BDN[qf][kf] = *(const float4*)&bondf[bondRow0 + (size_t)qf * 32768 +     \
                                                         kt2 + kf * 16 + g * 4];             \
        }                                                                                    \
        asm volatile("s_waitcnt vmcnt(" #WAITN ")" ::: "memory");                            \
        __builtin_amdgcn_s_barrier();                                                        \
        __builtin_amdgcn_sched_barrier(0);                                                   \
        /* QK^T kf=0,1 */                                                                    \
        f32x4 st[2][4];                                                                      \
        {                                                                                    \
            bf16x8 kfr[2][2];                                                                \
            _Pragma("unroll")                                                                \
            for (int kz = 0; kz < 2; ++kz)                                                   \
                _Pragma("unroll")                                                            \
                for (int kf = 0; kf < 2; ++kf)                                               \
                    kfr[kz][kf] = *(const bf16x8*)((const char*)&Ks[CUR][0] +                \
                                    (kf * 16 + r) * 128 + (((kz * 4 + g) ^ sw) * 16));       \
            _Pragma("unroll")                                                                \
            for (int qf = 0; qf < 2; ++qf)                                                   \
                _Pragma("unroll")                                                            \
                for (int kf = 0; kf < 2; ++kf) st[qf][kf] = zero4;                           \
            __builtin_amdgcn_s_setprio(1);                                                   \
            _Pragma("unroll")                                                                \
            for (int kz = 0; kz < 2; ++kz)                                                   \
                _Pragma("unroll")                                                            \
                for (int qf = 0; qf < 2; ++qf)                                               \
                    _Pragma("unroll")                                                        \
                    for (int kf = 0; kf < 2; ++kf)                                           \
                        st[qf][kf] = __builtin_amdgcn_mfma_f32_16x16x32_bf16(                \
                            kfr[kz][kf], aq[qf][kz], st[qf][kf], 0, 0, 0);                   \
            __builtin_amdgcn_s_setprio(0);                                                   \
        }                                                                                    \
        /* exp kf=0,1 -> ap0 */                                                              \
        bf16x8 ap0[2], ap1[2];                                                               \
        _Pragma("unroll")                                                                    \
        for (int qf = 0; qf < 2; ++qf) {                                                     \
            uint32_t pkl[2], pkh[2];                                                         \
            _Pragma("unroll")                                                                \
            for (int kf = 0; kf < 2; ++kf) {                                                 \
                const float p0 = vexp2(st[qf][kf][0] * BD[qf][kf].x);                        \
                const float p1 = vexp2(st[qf][kf][1] * BD[qf][kf].y);                        \
                const float p2 = vexp2(st[qf][kf][2] * BD[qf][kf].z);                        \
                const float p3 = vexp2(st[qf][kf][3] * BD[qf][kf].w);                        \
                sm[qf] += (p0 + p1) + (p2 + p3);                                             \
                pkl[kf] = cvtpk(p0, p1);                                                     \
                pkh[kf] = cvtpk(p2, p3);                                                     \
            }                                                                                \
            plswap16(pkl[0], pkl[1]);                                                        \
            plswap16(pkh[0], pkh[1]);                                                        \
            union { uint32_t u[4]; bf16x8 v; } a_;                                           \
            a_.u[0] = pkl[0]; a_.u[1] = pkh[0]; a_.u[2] = pkl[1]; a_.u[3] = pkh[1];          \
            ap0[qf] = a_.v;                                                                  \
        }                                                                                    \
        /* QK^T kf=2,3 */                                                                    \
        {                                                                                    \
            bf16x8 kfr[2][2];                                                                \
            _Pragma("unroll")                                                                \
            for (int kz = 0; kz < 2; ++kz)                                                   \
                _Pragma("unroll")                                                            \
                for (int kf = 0; kf < 2; ++kf)                                               \
                    kfr[kz][kf] = *(const bf16x8*)((const char*)&Ks[CUR][0] +                \
                                    ((kf + 2) * 16 + r) * 128 + (((kz * 4 + g) ^ sw) * 16)); \
            _Pragma("unroll")                                                                \
            for (int qf = 0; qf < 2; ++qf)                                                   \
                _Pragma("unroll")                                                            \
                for (int kf = 0; kf < 2; ++kf) st[qf][kf + 2] = zero4;                       \
            __builtin_amdgcn_s_setprio(1);                                                   \
            _Pragma("unroll")                                                                \
            for (int kz = 0; kz < 2; ++kz)                                                   \
                _Pragma("unroll")                                                            \
                for (int qf = 0; qf < 2; ++qf)                                               \
                    _Pragma("unroll")                                                        \
                    for (int kf = 0; kf < 2; ++kf)                                           \
                        st[qf][kf + 2] = __builtin_amdgcn_mfma_f32_16x16x32_bf16(            \
                            kfr[kz][kf], aq[qf][kz], st[qf][kf + 2], 0, 0, 0);               \
            __builtin_amdgcn_s_setprio(0);                                                   \
        }                                                                                    \
        /* PV kz=0 */                                                                        \
        {                                                                                    \
            bf16x8 bv_[4];                                                                   \
            _Pragma("unroll")                                                                \
            for (int nf = 0; nf < 4; ++nf)                                                   \
                bv_[nf] = *(const bf16x8*)((const char*)&Vs[CUR][0] +                        \
                            (nf * 16 + r) * 128 + ((pg ^ sw) * 16));                         \
            __builtin_amdgcn_s_setprio(1);                                                   \
            _Pragma("unroll")                                                                \
            for (int qf = 0; qf < 2; ++qf)                                                   \
                _Pragma("unroll")                                                            \
                for (int nf = 0; nf < 4; ++nf)                                               \
                    o[qf][nf] = __builtin_amdgcn_mfma_f32_16x16x32_bf16(                     \
                        ap0[qf], bv_[nf], o[qf][nf], 0, 0, 0);                               \
            __builtin_amdgcn_s_setprio(0);                                                   \
        }                                                                                    \
        /* exp kf=2,3 -> ap1 */                                                              \
        _Pragma("unroll")                                                                    \
        for (int qf = 0; qf < 2; ++qf) {                                                     \
            uint32_t pkl[2], pkh[2];                                                         \
            _Pragma("unroll")                                                                \
            for (int kf = 0; kf < 2; ++kf) {                                                 \
                const float p0 = vexp2(st[qf][kf + 2][0] * BD[qf][kf + 2].x);                \
                const float p1 = vexp2(st[qf][kf + 2][1] * BD[qf][kf + 2].y);                \
                const float p2 = vexp2(st[qf][kf + 2][2] * BD[qf][kf + 2].z);                \
                const float p3 = vexp2(st[qf][kf + 2][3] * BD[qf][kf + 2].w);                \
                sm[qf] += (p0 + p1) + (p2 + p3);                                             \
                pkl[kf] = cvtpk(p0, p1);                                                     \
                pkh[kf] = cvtpk(p2, p3);                                                     \
            }                                                                                \
            plswap16(pkl[0], pkl[1]);                                                        \
            plswap16(pkh[0], pkh[1]);                                                        \
            union { uint32_t u[4]; bf16x8 v; } a_;                                           \
            a_.u[0] = pkl[0]; a_.u[1] = pkh[0]; a_.u[2] = pkl[1]; a_.u[3] = pkh[1];          \
            ap1[qf] = a_.v;                                                                  \
        }                                                                                    \
        /* PV kz=1 */                                                                        \
        {                                                                                    \
            bf16x8 bv_[4];                                                                   \
            _Pragma("unroll")                                                                \
            for (int nf = 0; nf < 4; ++nf)                                                   \
                bv_[nf] = *(const bf16x8*)((const char*)&Vs[CUR][0] +                        \
                            (nf * 16 + r) * 128 + (((4 + pg) ^ sw) * 16));                   \
            __builtin_amdgcn_s_setprio(1);                                                   \
            _Pragma("unroll")                                                                \
            for (int qf = 0; qf < 2; ++qf)                                                   \
                _Pragma("unroll")                                                            \
                for (int nf = 0; nf < 4; ++nf)                                               \
                    o[qf][nf] = __builtin_amdgcn_mfma_f32_16x16x32_bf16(                     \
                        ap1[qf], bv_[nf], o[qf][nf], 0, 0, 0);                               \
            __builtin_amdgcn_s_setprio(0);                                                   \
        }                                                                                    \
        __builtin_amdgcn_sched_barrier(0);                                                   \
        __builtin_amdgcn_s_barrier();                                                        \
        kt += 64;                                                                            \
    }

__global__ __launch_bounds__(128, 2) void attn_kernel(
    const u16* __restrict__ qb, const u16* __restrict__ kb,
    const u16* __restrict__ vtb, const float* __restrict__ bondf,
    u16* __restrict__ attnout)
{
    __shared__ u16 Ks[2][64 * 64];   // [buf][key][dk]   swizzled chunks
    __shared__ u16 Vs[2][64 * 64];   // [buf][dk][key]   swizzled chunks
    const int t = threadIdx.x;
    const int lane = t & 63, w = t >> 6;
    const int g = lane >> 4, r = lane & 15;
    const int sw = r & 7;
    const int pg = ((g & 1) << 1) | (g >> 1);   // key-chunk permutation from permlane16_swap
    const int flat = blockIdx.x;
    const int wg = (flat & 7) * 128 + (flat >> 3);
    const int bh = wg >> 5, qt = wg & 31;
    const int b = bh >> 4, h = bh & 15;
    const int q0 = qt * 64 + w * 32;
    const size_t kvBase = (size_t)bh * 2048 * 64;
    const size_t vtBase = (size_t)bh * 64 * 2048;
    const size_t bondRow0 = ((size_t)b * 2048 + q0 + r) * 2048;   // qf adds 32768

    // Q as B-operand fragments (pre-scaled by 1/8*log2e in the QKV epilogue)
    bf16x8 aq[2][2];
#pragma unroll
    for (int qf = 0; qf < 2; ++qf)
#pragma unroll
        for (int kz = 0; kz < 2; ++kz)
            aq[qf][kz] = *(const bf16x8*)&qb[kvBase + (size_t)(q0 + qf * 16 + r) * 64 + kz * 32 + g * 8];

    const f32x4 zero4 = {0.f, 0.f, 0.f, 0.f};
    f32x4 o[2][4];
#pragma unroll
    for (int qf = 0; qf < 2; ++qf)
#pragma unroll
        for (int nf = 0; nf < 4; ++nf) o[qf][nf] = zero4;
    float sm[2] = {0.f, 0.f};

    // prologue: stage K/V tile 0; bond tile 0 into bdA regs (16 vmem in flight)
#pragma unroll
    for (int i = 0; i < 4; ++i) {
        const int idx = i * 128 + t;
        const int row = idx >> 3, ch = idx & 7;
        const int chg = ch ^ (row & 7);
        gld16(kb + kvBase + (size_t)row * 64 + chg * 8, (char*)&Ks[0][0] + idx * 16);
        gld16(vtb + vtBase + (size_t)row * 2048 + chg * 8, (char*)&Vs[0][0] + idx * 16);
    }
    float4 bdA[2][4], bdB[2][4];
#pragma unroll
    for (int qf = 0; qf < 2; ++qf)
#pragma unroll
        for (int kf = 0; kf < 4; ++kf)
            bdA[qf][kf] = *(const float4*)&bondf[bondRow0 + (size_t)qf * 32768 + kf * 16 + g * 4];

    int kt = 0;
    for (int s = 0; s < 15; ++s) {
        ATTN_STEP(0, bdA, bdB, 1, 16)   // iters 0,2,..,28
        ATTN_STEP(1, bdB, bdA, 1, 16)   // iters 1,3,..,29
    }
    ATTN_STEP(0, bdA, bdB, 1, 16)       // iter 30 (stages tile 31)
    ATTN_STEP(1, bdB, bdA, 0, 0)        // iter 31 (drain)

    // row sums: reduce across the 4 g-groups, redistribute via width-16 shuffle
#pragma unroll
    for (int qf = 0; qf < 2; ++qf) {
        sm[qf] += __shfl_xor(sm[qf], 16, 64);
        sm[qf] += __shfl_xor(sm[qf], 32, 64);
    }
#pragma unroll
    for (int qf = 0; qf < 2; ++qf)
#pragma unroll
        for (int j = 0; j < 4; ++j) {
            const float inv = 1.f / __shfl(sm[qf], g * 4 + j, 16);
            const size_t orow = ((size_t)b * 2048 + q0 + qf * 16 + g * 4 + j) * 1024 + h * 64;
#pragma unroll
            for (int nf = 0; nf < 4; ++nf)
                attnout[orow + nf * 16 + r] = f2bf(o[qf][nf][j] * inv);
        }
}

// ---------------- launch ----------------

extern "C" void kernel_launch(void* const* d_in, const int* in_sizes, int n_in,
                              void* d_out, int out_size, void* d_ws, size_t ws_size,
                              hipStream_t stream) {
    (void)in_sizes; (void)n_in; (void)out_size; (void)ws_size;
    const float* x    = (const float*)d_in[0];
    const float* bond = (const float*)d_in[1];
    const float* Wq   = (const float*)d_in[2];
    const float* bq   = (const float*)d_in[3];
    const float* Wk   = (const float*)d_in[4];
    const float* bk   = (const float*)d_in[5];
    const float* Wv   = (const float*)d_in[6];
    const float* bv   = (const float*)d_in[7];
    const float* Wo   = (const float*)d_in[8];
    const float* bo   = (const float*)d_in[9];
    float* out = (float*)d_out;

    char* ws = (char*)d_ws;
    u16* xb      = (u16*)(ws);
    u16* wqkvt   = (u16*)(ws + 8388608);
    u16* wot     = (u16*)(ws + 14680064);
    u16* qb      = (u16*)(ws + 16777216);
    u16* kb_     = (u16*)(ws + 25165824);
    u16* vtb     = (u16*)(ws + 33554432);
    u16* attnout = (u16*)(ws + 58720256);

    dim3 tb(32, 8);
    transpose4_bf16_kernel<<<dim3(32, 32, 4), tb, 0, stream>>>(Wq, Wk, Wv, Wo, wqkvt, wot);
    cvt_bf16_kernel<<<1024, 256, 0, stream>>>(x, xb, 4194304 / 4, 1.0f);

    gemm128<0><<<dim3(24, 32), 256, 0, stream>>>(xb, wqkvt, bq, bk, bv, qb, kb_, vtb, nullptr);
    attn_kernel<<<dim3(1024), 128, 0, stream>>>(qb, kb_, vtb, bond, attnout);
    gemm128<1><<<dim3(8, 32), 256, 0, stream>>>(attnout, wot, bo, nullptr, nullptr,
                                                nullptr, nullptr, nullptr, out);
}